// Round 10
// baseline (563.865 us; speedup 1.0000x reference)
//
#include <hip/hip_runtime.h>
#include <hip/hip_fp16.h>

#define NUSERS 100000
#define NITEMS 50000
#define NN (NUSERS + NITEMS)          // 150000 nodes
#define D 64
#define NE 6400000
#define QB 1024
#define PSZ 256                        // nodes per partition
#define NP ((NN + PSZ - 1) / PSZ)      // 586 partitions
#define NBLKB 256                      // countB/placeB blocks
#define EPB (NE / NBLKB)               // 25000 edges per block (exact)
#define CNTN (NP * NBLKB)              // 150016 counts
#define PB_CHUNK 4096                  // placeB LDS-staged chunk
#define RIT ((NITEMS + 63) / 64)       // 782 rating item-tiles

typedef _Float16 half8 __attribute__((ext_vector_type(8)));
typedef float f32x4 __attribute__((ext_vector_type(4)));

// ---------------------------------------------------------------------------
// countB: per-block LDS histogram over partitions -> counts[p][b]. No global
// atomics anywhere in the CSR build.
// ---------------------------------------------------------------------------
__global__ __launch_bounds__(256) void countB_kernel(const int* __restrict__ dst,
                                                     int* __restrict__ counts) {
    __shared__ int hist[NP];
    const int t = threadIdx.x, b = blockIdx.x;
    for (int j = t; j < NP; j += 256) hist[j] = 0;
    __syncthreads();
    const int e0 = b * EPB, e1 = e0 + EPB;
    for (int i = e0 + t; i < e1; i += 256)
        atomicAdd(&hist[dst[i] >> 8], 1);            // LDS atomic
    __syncthreads();
    for (int j = t; j < NP; j += 256)
        counts[j * NBLKB + b] = hist[j];
}

// ---------------------------------------------------------------------------
// single-block exclusive scan, 16 elems/thread per chunk
// ---------------------------------------------------------------------------
__global__ __launch_bounds__(1024) void scan_kernel(const int* __restrict__ cnt,
                                                    int* __restrict__ out, int nn) {
    __shared__ int wsum[16];
    __shared__ int s_carry, s_tot;
    const int t = threadIdx.x;
    const int lane = t & 63;
    const int wid = t >> 6;
    if (t == 0) s_carry = 0;
    __syncthreads();
    const int CH = 16384;
    for (int chunk = 0; chunk < nn; chunk += CH) {
        const int i0 = chunk + t * 16;
        int c[16];
        if (i0 + 16 <= nn) {
#pragma unroll
            for (int q = 0; q < 4; ++q) {
                int4 v = *reinterpret_cast<const int4*>(cnt + i0 + q * 4);
                c[q * 4 + 0] = v.x; c[q * 4 + 1] = v.y;
                c[q * 4 + 2] = v.z; c[q * 4 + 3] = v.w;
            }
        } else {
#pragma unroll
            for (int q = 0; q < 16; ++q) c[q] = (i0 + q < nn) ? cnt[i0 + q] : 0;
        }
        int v = 0;
#pragma unroll
        for (int q = 0; q < 16; ++q) v += c[q];
        int s = v;
#pragma unroll
        for (int off = 1; off < 64; off <<= 1) {
            int y = __shfl_up(s, off, 64);
            if (lane >= off) s += y;
        }
        if (lane == 63) wsum[wid] = s;
        __syncthreads();
        if (t < 16) {
            int w = wsum[t];
            int ss = w;
#pragma unroll
            for (int off = 1; off < 16; off <<= 1) {
                int y = __shfl_up(ss, off, 16);
                if (t >= off) ss += y;
            }
            wsum[t] = ss - w;
            if (t == 15) s_tot = ss;
        }
        __syncthreads();
        int run = s_carry + wsum[wid] + (s - v);
        int o[16];
#pragma unroll
        for (int q = 0; q < 16; ++q) { o[q] = run; run += c[q]; }
        if (i0 + 16 <= nn) {
#pragma unroll
            for (int q = 0; q < 4; ++q)
                *reinterpret_cast<int4*>(out + i0 + q * 4) =
                    make_int4(o[q * 4], o[q * 4 + 1], o[q * 4 + 2], o[q * 4 + 3]);
        } else {
#pragma unroll
            for (int q = 0; q < 16; ++q) if (i0 + q < nn) out[i0 + q] = o[q];
        }
        __syncthreads();
        if (t == 0) s_carry += s_tot;
        __syncthreads();
    }
    if (t == 0) out[nn] = s_carry;
}

// ---------------------------------------------------------------------------
// placeB: per 4096-edge chunk, counting-sort by partition in LDS, then dump
// partition-ordered bursts into this block's (p,b) regions. Block-private
// LDS cursors; zero global atomics. 1024 threads -> 16 waves/CU.
// ---------------------------------------------------------------------------
__global__ __launch_bounds__(1024) void placeB_kernel(const int* __restrict__ src,
                                                      const int* __restrict__ dst,
                                                      const float* __restrict__ val,
                                                      const int* __restrict__ offs,
                                                      int2* __restrict__ tmp) {
    __shared__ int  cur[NP];               // running global cursor per partition
    __shared__ int  chist[NP];             // per-chunk counts
    __shared__ int  cbase[NP];             // per-chunk exclusive scan
    __shared__ int2 stage[PB_CHUNK];       // chunk edges sorted by partition
    __shared__ int  gpos[PB_CHUNK];        // global dest position per staged edge
    const int t = threadIdx.x, b = blockIdx.x;
    for (int p = t; p < NP; p += 1024) cur[p] = offs[p * NBLKB + b];
    const int e0 = b * EPB, e1 = e0 + EPB;
    for (int c0 = e0; c0 < e1; c0 += PB_CHUNK) {
        const int csize = min(PB_CHUNK, e1 - c0);
        for (int p = t; p < NP; p += 1024) chist[p] = 0;
        __syncthreads();
        // count + keep edges in registers
        int  ep[4], eslot[4];
        int2 epay[4];
#pragma unroll
        for (int q = 0; q < 4; ++q) {
            int i = c0 + t + q * 1024;
            ep[q] = -1;
            if (i < e1) {
                int d = dst[i];
                int p = d >> 8;
                ep[q] = p;
                epay[q] = make_int2(src[i] | ((d & (PSZ - 1)) << 18),
                                    __float_as_int(val[i]));
                eslot[q] = atomicAdd(&chist[p], 1);   // LDS atomic
            }
        }
        __syncthreads();
        // wave 0: exclusive scan of chist[0..NP) -> cbase
        if (t < 64) {
            const int per = (NP + 63) / 64;           // 10
            int base = t * per;
            int loc[(NP + 63) / 64];
            int run = 0;
#pragma unroll
            for (int q = 0; q < (NP + 63) / 64; ++q) {
                int idx = base + q;
                int c = (idx < NP) ? chist[idx] : 0;
                loc[q] = run; run += c;
            }
            int s = run;
#pragma unroll
            for (int off = 1; off < 64; off <<= 1) {
                int y = __shfl_up(s, off, 64);
                if (t >= off) s += y;
            }
            int excl = s - run;
#pragma unroll
            for (int q = 0; q < (NP + 63) / 64; ++q) {
                int idx = base + q;
                if (idx < NP) cbase[idx] = excl + loc[q];
            }
        }
        __syncthreads();
        // stage sorted by partition
#pragma unroll
        for (int q = 0; q < 4; ++q) {
            if (ep[q] >= 0) {
                int s = cbase[ep[q]] + eslot[q];
                stage[s] = epay[q];
                gpos[s]  = cur[ep[q]] + eslot[q];
            }
        }
        __syncthreads();
        // dump bursts + advance cursors
        for (int k = t; k < csize; k += 1024)
            tmp[gpos[k]] = stage[k];
        for (int p = t; p < NP; p += 1024) cur[p] += chist[p];
        __syncthreads();
    }
}

// ---------------------------------------------------------------------------
// phaseC: one block per partition, 1024 threads. Pass 1: LDS node hist + scan
// -> row_start. Pass 2: exact placement into an ~87KB L2-resident CSR window.
// ---------------------------------------------------------------------------
__global__ __launch_bounds__(1024) void phaseC_kernel(const int2* __restrict__ tmp,
                                                      const int* __restrict__ offs,
                                                      int* __restrict__ row_start,
                                                      int2* __restrict__ csr) {
    __shared__ int hist[PSZ];
    __shared__ int cur[PSZ];
    __shared__ int wsum[4];
    const int p = blockIdx.x;
    const int t = threadIdx.x;
    const int lane = t & 63, wid = t >> 6;
    const int node0 = p * PSZ;
    const int nloc = min(PSZ, NN - node0);
    const int rb = offs[p * NBLKB];
    const int re = (p == NP - 1) ? NE : offs[(p + 1) * NBLKB];
    if (t < PSZ) hist[t] = 0;
    __syncthreads();
    for (int i = rb + t; i < re; i += 1024)
        atomicAdd(&hist[tmp[i].x >> 18], 1);         // LDS atomic
    __syncthreads();
    int v = 0, s = 0;
    if (t < PSZ) {
        v = hist[t];
        s = v;
#pragma unroll
        for (int off = 1; off < 64; off <<= 1) {
            int y = __shfl_up(s, off, 64);
            if (lane >= off) s += y;
        }
        if (lane == 63) wsum[wid] = s;
    }
    __syncthreads();
    if (t == 0) {
        int a = wsum[0], b2 = wsum[1], c = wsum[2];
        wsum[1] = a; wsum[2] = a + b2; wsum[3] = a + b2 + c; wsum[0] = 0;
    }
    __syncthreads();
    if (t < PSZ) {
        int base = rb + wsum[wid] + (s - v);
        cur[t] = base;
        if (t < nloc) row_start[node0 + t] = base;
    }
    if (p == 0 && t == 0) row_start[NN] = NE;
    __syncthreads();
    for (int i = rb + t; i < re; i += 1024) {
        int2 e = tmp[i];
        int dl = e.x >> 18;
        int pos = atomicAdd(&cur[dl], 1);            // LDS atomic
        csr[pos] = make_int2(e.x & 0x3FFFF, e.y);
    }
}

// ---------------------------------------------------------------------------
// conv0: x0h = fp16(concat(user_emb, item_emb))
// ---------------------------------------------------------------------------
__global__ __launch_bounds__(256) void conv0_kernel(const float4* __restrict__ ue4,
                                                    const float4* __restrict__ ie4,
                                                    ushort4* __restrict__ x0) {
    const int U4 = NUSERS * (D / 4);
    const int T4 = NN * (D / 4);
    int i = blockIdx.x * 256 + threadIdx.x;
    if (i >= T4) return;
    float4 v = (i < U4) ? ue4[i] : ie4[i - U4];
    x0[i] = make_ushort4(__half_as_ushort(__float2half_rn(v.x)),
                         __half_as_ushort(__float2half_rn(v.y)),
                         __half_as_ushort(__float2half_rn(v.z)),
                         __half_as_ushort(__float2half_rn(v.w)));
}

// ---------------------------------------------------------------------------
// NEW wide gather: 4 edges per VMEM instruction. 16 lanes per edge, each lane
// loads dwordx2 (4 fp16 dims). 8 instructions cover 32 edges -> 32 row
// fetches in flight per wave (vs 8 before), 0.5 VMEM instr/edge (vs 2).
// Per-lane acc = float4 over dims [4*(lane&15), +4) for edge slots
// eg = lane>>4 (mod 4); folded at row end via shfl_xor 16/32.
// ---------------------------------------------------------------------------
#define GATHER4(IDX_EXPR, PRED)                                                \
    {                                                                          \
        _Pragma("unroll")                                                      \
        for (int q = 0; q < 8; ++q) {                                          \
            int idx = (IDX_EXPR);                                              \
            int cidx; float vw;                                                \
            if (PRED) { cidx = idx; vw = 0.f; }                                \
            else      { cidx = idx; vw = 0.f; }                                \
        }                                                                      \
    }

template <int M>
__global__ __launch_bounds__(256) void spmm_kernel(const __half* __restrict__ xh,
                                                   const float* __restrict__ ie,
                                                   __half* __restrict__ xout,
                                                   float* __restrict__ acc_items,
                                                   const int* __restrict__ row_start,
                                                   const int2* __restrict__ csr) {
    int wave = (blockIdx.x << 2) | (threadIdx.x >> 6);
    int row = __builtin_amdgcn_readfirstlane(wave);
    if (row >= NN) return;
    const int lane = threadIdx.x & 63;
    const int eg = lane >> 4;            // edge slot 0..3
    const int d4 = (lane & 15) << 2;     // dim base
    int b = __builtin_amdgcn_readfirstlane(row_start[row]);
    int e = __builtin_amdgcn_readfirstlane(row_start[row + 1]);
    float4 a = make_float4(0.f, 0.f, 0.f, 0.f);
    int i = b;
    for (; i + 32 <= e; i += 32) {
#pragma unroll
        for (int q = 0; q < 8; ++q) {
            const int2 E = csr[i + q * 4 + eg];
            const uint2 hv = *reinterpret_cast<const uint2*>(xh + (size_t)E.x * D + d4);
            const float v = __int_as_float(E.y);
            const float2 f01 = __half22float2(*reinterpret_cast<const __half2*>(&hv.x));
            const float2 f23 = __half22float2(*reinterpret_cast<const __half2*>(&hv.y));
            a.x = fmaf(v, f01.x, a.x);
            a.y = fmaf(v, f01.y, a.y);
            a.z = fmaf(v, f23.x, a.z);
            a.w = fmaf(v, f23.y, a.w);
        }
    }
    if (i < e) {                          // predicated tail (<32 edges)
#pragma unroll
        for (int q = 0; q < 8; ++q) {
            const int idx = i + q * 4 + eg;
            const int cidx = (idx < e) ? idx : b;
            const int2 E = csr[cidx];
            const uint2 hv = *reinterpret_cast<const uint2*>(xh + (size_t)E.x * D + d4);
            const float v = (idx < e) ? __int_as_float(E.y) : 0.f;
            const float2 f01 = __half22float2(*reinterpret_cast<const __half2*>(&hv.x));
            const float2 f23 = __half22float2(*reinterpret_cast<const __half2*>(&hv.y));
            a.x = fmaf(v, f01.x, a.x);
            a.y = fmaf(v, f01.y, a.y);
            a.z = fmaf(v, f23.x, a.z);
            a.w = fmaf(v, f23.y, a.w);
        }
    }
    // fold the 4 edge-slot groups (lanes differing in bits 4/5; lane&15 kept)
    a.x += __shfl_xor(a.x, 16); a.y += __shfl_xor(a.y, 16);
    a.z += __shfl_xor(a.z, 16); a.w += __shfl_xor(a.w, 16);
    a.x += __shfl_xor(a.x, 32); a.y += __shfl_xor(a.y, 32);
    a.z += __shfl_xor(a.z, 32); a.w += __shfl_xor(a.w, 32);
    if (lane < 16) {
        __half2 lo = __floats2half2_rn(a.x, a.y);
        __half2 hi = __floats2half2_rn(a.z, a.w);
        uint2 pk;
        pk.x = *reinterpret_cast<unsigned int*>(&lo);
        pk.y = *reinterpret_cast<unsigned int*>(&hi);
        *reinterpret_cast<uint2*>(xout + (size_t)row * D + d4) = pk;
        if (row >= NUSERS) {
            size_t o = (size_t)(row - NUSERS) * D + d4;
            float4* ap = reinterpret_cast<float4*>(acc_items + o);
            if (M == 0) {
                const float4 iv = *reinterpret_cast<const float4*>(ie + o);
                *ap = make_float4(iv.x + a.x, iv.y + a.y, iv.z + a.z, iv.w + a.w);
            } else {
                const float4 c = *ap;
                *ap = make_float4(c.x + a.x, c.y + a.y, c.z + a.z, c.w + a.w);
            }
        }
    }
}

// ---------------------------------------------------------------------------
// layer-3 SpMM over ITEM rows only (wide gather); items_h = fp16(acc + a)
// ---------------------------------------------------------------------------
__global__ __launch_bounds__(256) void spmm_items_kernel(const __half* __restrict__ x2h,
                                                         const float* __restrict__ acc_items,
                                                         const int* __restrict__ row_start,
                                                         const int2* __restrict__ csr,
                                                         _Float16* __restrict__ items_h) {
    int wave = (blockIdx.x << 2) | (threadIdx.x >> 6);
    int it = __builtin_amdgcn_readfirstlane(wave);
    if (it >= NITEMS) return;
    const int row = NUSERS + it;
    const int lane = threadIdx.x & 63;
    const int eg = lane >> 4;
    const int d4 = (lane & 15) << 2;
    int b = __builtin_amdgcn_readfirstlane(row_start[row]);
    int e = __builtin_amdgcn_readfirstlane(row_start[row + 1]);
    float4 a = make_float4(0.f, 0.f, 0.f, 0.f);
    int i = b;
    for (; i + 32 <= e; i += 32) {
#pragma unroll
        for (int q = 0; q < 8; ++q) {
            const int2 E = csr[i + q * 4 + eg];
            const uint2 hv = *reinterpret_cast<const uint2*>(x2h + (size_t)E.x * D + d4);
            const float v = __int_as_float(E.y);
            const float2 f01 = __half22float2(*reinterpret_cast<const __half2*>(&hv.x));
            const float2 f23 = __half22float2(*reinterpret_cast<const __half2*>(&hv.y));
            a.x = fmaf(v, f01.x, a.x);
            a.y = fmaf(v, f01.y, a.y);
            a.z = fmaf(v, f23.x, a.z);
            a.w = fmaf(v, f23.y, a.w);
        }
    }
    if (i < e) {
#pragma unroll
        for (int q = 0; q < 8; ++q) {
            const int idx = i + q * 4 + eg;
            const int cidx = (idx < e) ? idx : b;
            const int2 E = csr[cidx];
            const uint2 hv = *reinterpret_cast<const uint2*>(x2h + (size_t)E.x * D + d4);
            const float v = (idx < e) ? __int_as_float(E.y) : 0.f;
            const float2 f01 = __half22float2(*reinterpret_cast<const __half2*>(&hv.x));
            const float2 f23 = __half22float2(*reinterpret_cast<const __half2*>(&hv.y));
            a.x = fmaf(v, f01.x, a.x);
            a.y = fmaf(v, f01.y, a.y);
            a.z = fmaf(v, f23.x, a.z);
            a.w = fmaf(v, f23.y, a.w);
        }
    }
    a.x += __shfl_xor(a.x, 16); a.y += __shfl_xor(a.y, 16);
    a.z += __shfl_xor(a.z, 16); a.w += __shfl_xor(a.w, 16);
    a.x += __shfl_xor(a.x, 32); a.y += __shfl_xor(a.y, 32);
    a.z += __shfl_xor(a.z, 32); a.w += __shfl_xor(a.w, 32);
    if (lane < 16) {
        size_t o = (size_t)it * D + d4;
        const float4 c = *reinterpret_cast<const float4*>(acc_items + o);
        __half2 lo = __floats2half2_rn(c.x + a.x, c.y + a.y);
        __half2 hi = __floats2half2_rn(c.z + a.z, c.w + a.w);
        uint2 pk;
        pk.x = *reinterpret_cast<unsigned int*>(&lo);
        pk.y = *reinterpret_cast<unsigned int*>(&hi);
        *reinterpret_cast<uint2*>(items_h + o) = pk;
    }
}

// ---------------------------------------------------------------------------
// gather helper (old layout, lane=dim) — kept for the tiny user_final kernel
// ---------------------------------------------------------------------------
#define GATHER_LOOP_H(XH)                                                      \
    {                                                                          \
        int i = b;                                                             \
        for (; i + 8 <= e; i += 8) {                                           \
            int2 E[8];                                                         \
            _Pragma("unroll")                                                  \
            for (int q = 0; q < 8; ++q) E[q] = csr[i + q];                     \
            float r[8];                                                        \
            _Pragma("unroll")                                                  \
            for (int q = 0; q < 8; ++q)                                        \
                r[q] = __half2float(XH[(size_t)E[q].x * D + lane]);            \
            _Pragma("unroll")                                                  \
            for (int q = 0; q < 8; ++q)                                        \
                a = fmaf(__int_as_float(E[q].y), r[q], a);                     \
        }                                                                      \
        for (; i < e; ++i) {                                                   \
            int2 e0 = csr[i];                                                  \
            a = fmaf(__int_as_float(e0.y),                                     \
                     __half2float(XH[(size_t)e0.x * D + lane]), a);            \
        }                                                                      \
    }

// ---------------------------------------------------------------------------
// layer-3 for the QB queried users only (one wave per query):
// ug_h = fp16((e0 + x1 + x2 + gather(x2)) / 16)
// ---------------------------------------------------------------------------
__global__ __launch_bounds__(256) void user_final_kernel(const float* __restrict__ ue,
                                                         const __half* __restrict__ x1h,
                                                         const __half* __restrict__ x2h,
                                                         const int* __restrict__ users,
                                                         const int* __restrict__ row_start,
                                                         const int2* __restrict__ csr,
                                                         _Float16* __restrict__ ug_h) {
    int w = (blockIdx.x << 2) | (threadIdx.x >> 6);   // 0..QB-1
    if (w >= QB) return;
    const int lane = threadIdx.x & 63;
    int row = __builtin_amdgcn_readfirstlane(users[w]);
    int b = __builtin_amdgcn_readfirstlane(row_start[row]);
    int e = __builtin_amdgcn_readfirstlane(row_start[row + 1]);
    float a = 0.f;
    GATHER_LOOP_H(x2h)
    size_t o = (size_t)row * D + lane;
    const float sc = 1.0f / 16.0f;                    // two folded /4 means
    ug_h[(size_t)w * D + lane] =
        (_Float16)((ue[o] + __half2float(x1h[o]) + __half2float(x2h[o]) + a) * sc);
}

// ---------------------------------------------------------------------------
// rating v4: MFMA fp16 GEMM. Wave = 16 users x 64 items, K=64 via two
// mfma_f32_16x16x32_f16 per 16x16 tile. Layout verified in round 9.
// ---------------------------------------------------------------------------
__global__ __launch_bounds__(256) void rating_kernel(const _Float16* __restrict__ items_h,
                                                     const _Float16* __restrict__ ug_h,
                                                     float* __restrict__ out) {
    const int lane = threadIdx.x & 63;
    const int w = threadIdx.x >> 6;
    const int u0 = blockIdx.y * 64 + w * 16;          // 16 users per wave
    const int i0 = blockIdx.x * 64;                   // 64 items per block
    const int lr  = lane & 15;
    const int kb8 = (lane >> 4) * 8;                  // k-offset in 32-k block

    const int urow = u0 + lr;
    const half8 a0 = *reinterpret_cast<const half8*>(ug_h + urow * D + kb8);
    const half8 a1 = *reinterpret_cast<const half8*>(ug_h + urow * D + 32 + kb8);

    f32x4 acc[4];
    half8 b0[4], b1[4];
#pragma unroll
    for (int sub = 0; sub < 4; ++sub) {
        int irow = i0 + sub * 16 + lr;
        irow = (irow < NITEMS) ? irow : (NITEMS - 1);
        b0[sub] = *reinterpret_cast<const half8*>(items_h + (size_t)irow * D + kb8);
        b1[sub] = *reinterpret_cast<const half8*>(items_h + (size_t)irow * D + 32 + kb8);
        acc[sub] = {0.f, 0.f, 0.f, 0.f};
    }
#pragma unroll
    for (int sub = 0; sub < 4; ++sub) {
        acc[sub] = __builtin_amdgcn_mfma_f32_16x16x32_f16(a0, b0[sub], acc[sub], 0, 0, 0);
        acc[sub] = __builtin_amdgcn_mfma_f32_16x16x32_f16(a1, b1[sub], acc[sub], 0, 0, 0);
    }
    const int ubase = u0 + (lane >> 4) * 4;
#pragma unroll
    for (int sub = 0; sub < 4; ++sub) {
        const int item = i0 + sub * 16 + lr;
        if (item < NITEMS) {
#pragma unroll
            for (int r = 0; r < 4; ++r) {
                float sg = 1.0f / (1.0f + __expf(-acc[sub][r]));
                __builtin_nontemporal_store(sg, &out[(size_t)(ubase + r) * NITEMS + item]);
            }
        }
    }
}

extern "C" void kernel_launch(void* const* d_in, const int* in_sizes, int n_in,
                              void* d_out, int out_size, void* d_ws, size_t ws_size,
                              hipStream_t stream) {
    const float* user_emb = (const float*)d_in[0];
    const float* item_emb = (const float*)d_in[1];
    const float* edge_val = (const float*)d_in[2];
    const int*   edge_src = (const int*)d_in[3];
    const int*   edge_dst = (const int*)d_in[4];
    const int*   users    = (const int*)d_in[5];

    // d_out (204.8 MB) doubles as scratch; rating_kernel rewrites all of it
    // and reads only from d_ws. Total scratch use: ~174.6 MB.
    float*  ob  = (float*)d_out;
    int2*   csr = (int2*)ob;                           // 51.2 MB
    int2*   tmp = csr + NE;                            // 51.2 MB
    __half* x0h = (__half*)(tmp + NE);                 // 19.2 MB
    __half* x1h = x0h + (size_t)NN * D;                // 19.2 MB
    __half* x2h = x1h + (size_t)NN * D;                // 19.2 MB
    float*  acc = (float*)(x2h + (size_t)NN * D);      // 12.8 MB (items only)
    int*    row_start = (int*)(acc + (size_t)NITEMS * D); // 150080 ints
    int*    counts    = row_start + 150080;            // 150016 ints
    int*    offs      = counts + CNTN;                 // 150080 ints

    // d_ws: only what rating_kernel reads (~6.6 MB, fp16)
    _Float16* items_h = (_Float16*)d_ws;               // NITEMS*D fp16
    _Float16* ug_h    = items_h + (size_t)NITEMS * D;  // QB*D fp16

    // CSR build — zero global atomics
    countB_kernel<<<NBLKB, 256, 0, stream>>>(edge_dst, counts);
    scan_kernel<<<1, 1024, 0, stream>>>(counts, offs, CNTN);
    placeB_kernel<<<NBLKB, 1024, 0, stream>>>(edge_src, edge_dst, edge_val, offs, tmp);
    phaseC_kernel<<<NP, 1024, 0, stream>>>(tmp, offs, row_start, csr);

    // fp16 copy of the embedding tables (layer-1 gather source)
    conv0_kernel<<<(NN * (D / 4) + 255) / 256, 256, 0, stream>>>(
        (const float4*)user_emb, (const float4*)item_emb, (ushort4*)x0h);

    // layer 1 + layer 2 over all rows (fp16 wide gather, f32 accumulate)
    spmm_kernel<0><<<37500, 256, 0, stream>>>(x0h, item_emb, x1h, acc, row_start, csr);
    spmm_kernel<1><<<37500, 256, 0, stream>>>(x1h, nullptr, x2h, acc, row_start, csr);
    // layer 3: item rows only + queried users
    spmm_items_kernel<<<12500, 256, 0, stream>>>(x2h, acc, row_start, csr, items_h);
    user_final_kernel<<<QB / 4, 256, 0, stream>>>(user_emb, x1h, x2h, users,
                                                  row_start, csr, ug_h);

    rating_kernel<<<dim3(RIT, QB / 64), 256, 0, stream>>>(items_h, ug_h, (float*)d_out);
}

// Round 11
// 524.960 us; speedup vs baseline: 1.0741x; 1.0741x over previous
//
#include <hip/hip_runtime.h>
#include <hip/hip_fp16.h>

#define NUSERS 100000
#define NITEMS 50000
#define NN (NUSERS + NITEMS)          // 150000 nodes
#define D 64
#define NE 6400000
#define QB 1024
#define PSZ 256                        // nodes per partition
#define NP ((NN + PSZ - 1) / PSZ)      // 586 partitions
#define NBLKB 256                      // countB/placeB blocks
#define EPB (NE / NBLKB)               // 25000 edges per block (exact)
#define CNTN (NP * NBLKB)              // 150016 counts
#define PB_CHUNK 4096                  // placeB LDS-staged chunk
#define RIT ((NITEMS + 63) / 64)       // 782 rating item-tiles
#define ITEM_BLKS 12500                // spmm_items blocks (wave per item)
#define CONV_BLKS ((NN * (D / 4) + 1023) / 1024)   // 2344

typedef _Float16 half8 __attribute__((ext_vector_type(8)));
typedef float f32x4 __attribute__((ext_vector_type(4)));

// ---------------------------------------------------------------------------
// countB: per-block LDS histogram over partitions -> counts[p][b]. No global
// atomics anywhere in the CSR build.
// ---------------------------------------------------------------------------
__global__ __launch_bounds__(256) void countB_kernel(const int* __restrict__ dst,
                                                     int* __restrict__ counts) {
    __shared__ int hist[NP];
    const int t = threadIdx.x, b = blockIdx.x;
    for (int j = t; j < NP; j += 256) hist[j] = 0;
    __syncthreads();
    const int e0 = b * EPB, e1 = e0 + EPB;
    for (int i = e0 + t; i < e1; i += 256)
        atomicAdd(&hist[dst[i] >> 8], 1);            // LDS atomic
    __syncthreads();
    for (int j = t; j < NP; j += 256)
        counts[j * NBLKB + b] = hist[j];
}

// ---------------------------------------------------------------------------
// scan + conv0 fused: block 0 runs the serial exclusive scan (1024 threads,
// 16 elems/thread/chunk); blocks 1..CONV_BLKS convert the f32 embedding
// tables to fp16 x0h on the otherwise-idle CUs.
// ---------------------------------------------------------------------------
__global__ __launch_bounds__(1024) void scan_kernel(const int* __restrict__ cnt,
                                                    int* __restrict__ out, int nn,
                                                    const float4* __restrict__ ue4,
                                                    const float4* __restrict__ ie4,
                                                    ushort4* __restrict__ x0) {
    if (blockIdx.x != 0) {                            // conv0 side-job
        const int U4 = NUSERS * (D / 4);
        const int T4 = NN * (D / 4);
        int i = (blockIdx.x - 1) * 1024 + threadIdx.x;
        if (i < T4) {
            float4 v = (i < U4) ? ue4[i] : ie4[i - U4];
            x0[i] = make_ushort4(__half_as_ushort(__float2half_rn(v.x)),
                                 __half_as_ushort(__float2half_rn(v.y)),
                                 __half_as_ushort(__float2half_rn(v.z)),
                                 __half_as_ushort(__float2half_rn(v.w)));
        }
        return;
    }
    __shared__ int wsum[16];
    __shared__ int s_carry, s_tot;
    const int t = threadIdx.x;
    const int lane = t & 63;
    const int wid = t >> 6;
    if (t == 0) s_carry = 0;
    __syncthreads();
    const int CH = 16384;
    for (int chunk = 0; chunk < nn; chunk += CH) {
        const int i0 = chunk + t * 16;
        int c[16];
        if (i0 + 16 <= nn) {
#pragma unroll
            for (int q = 0; q < 4; ++q) {
                int4 v = *reinterpret_cast<const int4*>(cnt + i0 + q * 4);
                c[q * 4 + 0] = v.x; c[q * 4 + 1] = v.y;
                c[q * 4 + 2] = v.z; c[q * 4 + 3] = v.w;
            }
        } else {
#pragma unroll
            for (int q = 0; q < 16; ++q) c[q] = (i0 + q < nn) ? cnt[i0 + q] : 0;
        }
        int v = 0;
#pragma unroll
        for (int q = 0; q < 16; ++q) v += c[q];
        int s = v;
#pragma unroll
        for (int off = 1; off < 64; off <<= 1) {
            int y = __shfl_up(s, off, 64);
            if (lane >= off) s += y;
        }
        if (lane == 63) wsum[wid] = s;
        __syncthreads();
        if (t < 16) {
            int w = wsum[t];
            int ss = w;
#pragma unroll
            for (int off = 1; off < 16; off <<= 1) {
                int y = __shfl_up(ss, off, 16);
                if (t >= off) ss += y;
            }
            wsum[t] = ss - w;
            if (t == 15) s_tot = ss;
        }
        __syncthreads();
        int run = s_carry + wsum[wid] + (s - v);
        int o[16];
#pragma unroll
        for (int q = 0; q < 16; ++q) { o[q] = run; run += c[q]; }
        if (i0 + 16 <= nn) {
#pragma unroll
            for (int q = 0; q < 4; ++q)
                *reinterpret_cast<int4*>(out + i0 + q * 4) =
                    make_int4(o[q * 4], o[q * 4 + 1], o[q * 4 + 2], o[q * 4 + 3]);
        } else {
#pragma unroll
            for (int q = 0; q < 16; ++q) if (i0 + q < nn) out[i0 + q] = o[q];
        }
        __syncthreads();
        if (t == 0) s_carry += s_tot;
        __syncthreads();
    }
    if (t == 0) out[nn] = s_carry;
}

// ---------------------------------------------------------------------------
// placeB: per 4096-edge chunk, counting-sort by partition in LDS, then dump
// partition-ordered bursts into this block's (p,b) regions. Block-private
// LDS cursors; zero global atomics. 1024 threads -> 16 waves/CU.
// ---------------------------------------------------------------------------
__global__ __launch_bounds__(1024) void placeB_kernel(const int* __restrict__ src,
                                                      const int* __restrict__ dst,
                                                      const float* __restrict__ val,
                                                      const int* __restrict__ offs,
                                                      int2* __restrict__ tmp) {
    __shared__ int  cur[NP];               // running global cursor per partition
    __shared__ int  chist[NP];             // per-chunk counts
    __shared__ int  cbase[NP];             // per-chunk exclusive scan
    __shared__ int2 stage[PB_CHUNK];       // chunk edges sorted by partition
    __shared__ int  gpos[PB_CHUNK];        // global dest position per staged edge
    const int t = threadIdx.x, b = blockIdx.x;
    for (int p = t; p < NP; p += 1024) cur[p] = offs[p * NBLKB + b];
    const int e0 = b * EPB, e1 = e0 + EPB;
    for (int c0 = e0; c0 < e1; c0 += PB_CHUNK) {
        const int csize = min(PB_CHUNK, e1 - c0);
        for (int p = t; p < NP; p += 1024) chist[p] = 0;
        __syncthreads();
        // count + keep edges in registers
        int  ep[4], eslot[4];
        int2 epay[4];
#pragma unroll
        for (int q = 0; q < 4; ++q) {
            int i = c0 + t + q * 1024;
            ep[q] = -1;
            if (i < e1) {
                int d = dst[i];
                int p = d >> 8;
                ep[q] = p;
                epay[q] = make_int2(src[i] | ((d & (PSZ - 1)) << 18),
                                    __float_as_int(val[i]));
                eslot[q] = atomicAdd(&chist[p], 1);   // LDS atomic
            }
        }
        __syncthreads();
        // wave 0: exclusive scan of chist[0..NP) -> cbase
        if (t < 64) {
            const int per = (NP + 63) / 64;           // 10
            int base = t * per;
            int loc[(NP + 63) / 64];
            int run = 0;
#pragma unroll
            for (int q = 0; q < (NP + 63) / 64; ++q) {
                int idx = base + q;
                int c = (idx < NP) ? chist[idx] : 0;
                loc[q] = run; run += c;
            }
            int s = run;
#pragma unroll
            for (int off = 1; off < 64; off <<= 1) {
                int y = __shfl_up(s, off, 64);
                if (t >= off) s += y;
            }
            int excl = s - run;
#pragma unroll
            for (int q = 0; q < (NP + 63) / 64; ++q) {
                int idx = base + q;
                if (idx < NP) cbase[idx] = excl + loc[q];
            }
        }
        __syncthreads();
        // stage sorted by partition
#pragma unroll
        for (int q = 0; q < 4; ++q) {
            if (ep[q] >= 0) {
                int s = cbase[ep[q]] + eslot[q];
                stage[s] = epay[q];
                gpos[s]  = cur[ep[q]] + eslot[q];
            }
        }
        __syncthreads();
        // dump bursts + advance cursors
        for (int k = t; k < csize; k += 1024)
            tmp[gpos[k]] = stage[k];
        for (int p = t; p < NP; p += 1024) cur[p] += chist[p];
        __syncthreads();
    }
}

// ---------------------------------------------------------------------------
// phaseC: one block per partition, 1024 threads. Pass 1: LDS node hist + scan
// -> row_start. Pass 2: exact placement into an ~87KB L2-resident CSR window.
// ---------------------------------------------------------------------------
__global__ __launch_bounds__(1024) void phaseC_kernel(const int2* __restrict__ tmp,
                                                      const int* __restrict__ offs,
                                                      int* __restrict__ row_start,
                                                      int2* __restrict__ csr) {
    __shared__ int hist[PSZ];
    __shared__ int cur[PSZ];
    __shared__ int wsum[4];
    const int p = blockIdx.x;
    const int t = threadIdx.x;
    const int lane = t & 63, wid = t >> 6;
    const int node0 = p * PSZ;
    const int nloc = min(PSZ, NN - node0);
    const int rb = offs[p * NBLKB];
    const int re = (p == NP - 1) ? NE : offs[(p + 1) * NBLKB];
    if (t < PSZ) hist[t] = 0;
    __syncthreads();
    for (int i = rb + t; i < re; i += 1024)
        atomicAdd(&hist[tmp[i].x >> 18], 1);         // LDS atomic
    __syncthreads();
    int v = 0, s = 0;
    if (t < PSZ) {
        v = hist[t];
        s = v;
#pragma unroll
        for (int off = 1; off < 64; off <<= 1) {
            int y = __shfl_up(s, off, 64);
            if (lane >= off) s += y;
        }
        if (lane == 63) wsum[wid] = s;
    }
    __syncthreads();
    if (t == 0) {
        int a = wsum[0], b2 = wsum[1], c = wsum[2];
        wsum[1] = a; wsum[2] = a + b2; wsum[3] = a + b2 + c; wsum[0] = 0;
    }
    __syncthreads();
    if (t < PSZ) {
        int base = rb + wsum[wid] + (s - v);
        cur[t] = base;
        if (t < nloc) row_start[node0 + t] = base;
    }
    if (p == 0 && t == 0) row_start[NN] = NE;
    __syncthreads();
    for (int i = rb + t; i < re; i += 1024) {
        int2 e = tmp[i];
        int dl = e.x >> 18;
        int pos = atomicAdd(&cur[dl], 1);            // LDS atomic
        csr[pos] = make_int2(e.x & 0x3FFFF, e.y);
    }
}

// ---------------------------------------------------------------------------
// gather helper over fp16 source rows (lane = dim), 8-deep MLP, f32 acc.
// Proven 127 us/layer (round 9); round-10 wide variant regressed — reverted.
// ---------------------------------------------------------------------------
#define GATHER_LOOP_H(XH)                                                      \
    {                                                                          \
        int i = b;                                                             \
        for (; i + 8 <= e; i += 8) {                                           \
            int2 E[8];                                                         \
            _Pragma("unroll")                                                  \
            for (int q = 0; q < 8; ++q) E[q] = csr[i + q];                     \
            float r[8];                                                        \
            _Pragma("unroll")                                                  \
            for (int q = 0; q < 8; ++q)                                        \
                r[q] = __half2float(XH[(size_t)E[q].x * D + lane]);            \
            _Pragma("unroll")                                                  \
            for (int q = 0; q < 8; ++q)                                        \
                a = fmaf(__int_as_float(E[q].y), r[q], a);                     \
        }                                                                      \
        for (; i < e; ++i) {                                                   \
            int2 e0 = csr[i];                                                  \
            a = fmaf(__int_as_float(e0.y),                                     \
                     __half2float(XH[(size_t)e0.x * D + lane]), a);            \
        }                                                                      \
    }

// ---------------------------------------------------------------------------
// SpMM layers 1-2 (all rows), fp16 in / fp16 out, f32 acc for item rows.
// M=0: src=x0h, acc_items = ie + a. M=1: src=x1h, acc_items += a.
// ---------------------------------------------------------------------------
template <int M>
__global__ __launch_bounds__(256) void spmm_kernel(const __half* __restrict__ xh,
                                                   const float* __restrict__ ie,
                                                   __half* __restrict__ xout,
                                                   float* __restrict__ acc_items,
                                                   const int* __restrict__ row_start,
                                                   const int2* __restrict__ csr) {
    int wave = (blockIdx.x << 2) | (threadIdx.x >> 6);
    int row = __builtin_amdgcn_readfirstlane(wave);
    if (row >= NN) return;
    const int lane = threadIdx.x & 63;
    int b = __builtin_amdgcn_readfirstlane(row_start[row]);
    int e = __builtin_amdgcn_readfirstlane(row_start[row + 1]);
    float a = 0.f;
    GATHER_LOOP_H(xh)
    xout[(size_t)row * D + lane] = __float2half_rn(a);
    if (row >= NUSERS) {
        size_t o = (size_t)(row - NUSERS) * D + lane;
        if (M == 0)
            acc_items[o] = ie[o] + a;
        else
            acc_items[o] += a;
    }
}

// ---------------------------------------------------------------------------
// layer-3 fused tail: blocks < ITEM_BLKS do the items-only SpMM
// (items_h = fp16(acc_items + a)); the remaining QB/4 blocks finish the
// queried users (ug_h = fp16((e0 + x1 + x2 + gather(x2)) / 16)).
// ---------------------------------------------------------------------------
__global__ __launch_bounds__(256) void tail3_kernel(const __half* __restrict__ x2h,
                                                    const float* __restrict__ acc_items,
                                                    const int* __restrict__ row_start,
                                                    const int2* __restrict__ csr,
                                                    _Float16* __restrict__ items_h,
                                                    const float* __restrict__ ue,
                                                    const __half* __restrict__ x1h,
                                                    const int* __restrict__ users,
                                                    _Float16* __restrict__ ug_h) {
    const int lane = threadIdx.x & 63;
    if (blockIdx.x < ITEM_BLKS) {
        int wave = (blockIdx.x << 2) | (threadIdx.x >> 6);
        int it = __builtin_amdgcn_readfirstlane(wave);
        if (it >= NITEMS) return;
        const int row = NUSERS + it;
        int b = __builtin_amdgcn_readfirstlane(row_start[row]);
        int e = __builtin_amdgcn_readfirstlane(row_start[row + 1]);
        float a = 0.f;
        GATHER_LOOP_H(x2h)
        size_t o = (size_t)it * D + lane;
        items_h[o] = (_Float16)(acc_items[o] + a);
    } else {
        int w = ((blockIdx.x - ITEM_BLKS) << 2) | (threadIdx.x >> 6);  // 0..QB-1
        if (w >= QB) return;
        int row = __builtin_amdgcn_readfirstlane(users[w]);
        int b = __builtin_amdgcn_readfirstlane(row_start[row]);
        int e = __builtin_amdgcn_readfirstlane(row_start[row + 1]);
        float a = 0.f;
        GATHER_LOOP_H(x2h)
        size_t o = (size_t)row * D + lane;
        const float sc = 1.0f / 16.0f;                // two folded /4 means
        ug_h[(size_t)w * D + lane] =
            (_Float16)((ue[o] + __half2float(x1h[o]) + __half2float(x2h[o]) + a) * sc);
    }
}

// ---------------------------------------------------------------------------
// rating: MFMA fp16 GEMM. Wave = 16 users x 64 items, K=64 via two
// mfma_f32_16x16x32_f16 per 16x16 tile. Layout verified in round 9.
// ---------------------------------------------------------------------------
__global__ __launch_bounds__(256) void rating_kernel(const _Float16* __restrict__ items_h,
                                                     const _Float16* __restrict__ ug_h,
                                                     float* __restrict__ out) {
    const int lane = threadIdx.x & 63;
    const int w = threadIdx.x >> 6;
    const int u0 = blockIdx.y * 64 + w * 16;          // 16 users per wave
    const int i0 = blockIdx.x * 64;                   // 64 items per block
    const int lr  = lane & 15;
    const int kb8 = (lane >> 4) * 8;                  // k-offset in 32-k block

    const int urow = u0 + lr;
    const half8 a0 = *reinterpret_cast<const half8*>(ug_h + urow * D + kb8);
    const half8 a1 = *reinterpret_cast<const half8*>(ug_h + urow * D + 32 + kb8);

    f32x4 acc[4];
    half8 b0[4], b1[4];
#pragma unroll
    for (int sub = 0; sub < 4; ++sub) {
        int irow = i0 + sub * 16 + lr;
        irow = (irow < NITEMS) ? irow : (NITEMS - 1);
        b0[sub] = *reinterpret_cast<const half8*>(items_h + (size_t)irow * D + kb8);
        b1[sub] = *reinterpret_cast<const half8*>(items_h + (size_t)irow * D + 32 + kb8);
        acc[sub] = {0.f, 0.f, 0.f, 0.f};
    }
#pragma unroll
    for (int sub = 0; sub < 4; ++sub) {
        acc[sub] = __builtin_amdgcn_mfma_f32_16x16x32_f16(a0, b0[sub], acc[sub], 0, 0, 0);
        acc[sub] = __builtin_amdgcn_mfma_f32_16x16x32_f16(a1, b1[sub], acc[sub], 0, 0, 0);
    }
    const int ubase = u0 + (lane >> 4) * 4;
#pragma unroll
    for (int sub = 0; sub < 4; ++sub) {
        const int item = i0 + sub * 16 + lr;
        if (item < NITEMS) {
#pragma unroll
            for (int r = 0; r < 4; ++r) {
                float sg = 1.0f / (1.0f + __expf(-acc[sub][r]));
                __builtin_nontemporal_store(sg, &out[(size_t)(ubase + r) * NITEMS + item]);
            }
        }
    }
}

extern "C" void kernel_launch(void* const* d_in, const int* in_sizes, int n_in,
                              void* d_out, int out_size, void* d_ws, size_t ws_size,
                              hipStream_t stream) {
    const float* user_emb = (const float*)d_in[0];
    const float* item_emb = (const float*)d_in[1];
    const float* edge_val = (const float*)d_in[2];
    const int*   edge_src = (const int*)d_in[3];
    const int*   edge_dst = (const int*)d_in[4];
    const int*   users    = (const int*)d_in[5];

    // d_out (204.8 MB) doubles as scratch; rating_kernel rewrites all of it
    // and reads only from d_ws. Total scratch use: ~174.6 MB.
    float*  ob  = (float*)d_out;
    int2*   csr = (int2*)ob;                           // 51.2 MB
    int2*   tmp = csr + NE;                            // 51.2 MB
    __half* x0h = (__half*)(tmp + NE);                 // 19.2 MB
    __half* x1h = x0h + (size_t)NN * D;                // 19.2 MB
    __half* x2h = x1h + (size_t)NN * D;                // 19.2 MB
    float*  acc = (float*)(x2h + (size_t)NN * D);      // 12.8 MB (items only)
    int*    row_start = (int*)(acc + (size_t)NITEMS * D); // 150080 ints
    int*    counts    = row_start + 150080;            // 150016 ints
    int*    offs      = counts + CNTN;                 // 150080 ints

    // d_ws: only what rating_kernel reads (~6.6 MB, fp16)
    _Float16* items_h = (_Float16*)d_ws;               // NITEMS*D fp16
    _Float16* ug_h    = items_h + (size_t)NITEMS * D;  // QB*D fp16

    // CSR build — zero global atomics. conv0 rides on scan's idle CUs.
    countB_kernel<<<NBLKB, 256, 0, stream>>>(edge_dst, counts);
    scan_kernel<<<1 + CONV_BLKS, 1024, 0, stream>>>(counts, offs, CNTN,
                                                    (const float4*)user_emb,
                                                    (const float4*)item_emb,
                                                    (ushort4*)x0h);
    placeB_kernel<<<NBLKB, 1024, 0, stream>>>(edge_src, edge_dst, edge_val, offs, tmp);
    phaseC_kernel<<<NP, 1024, 0, stream>>>(tmp, offs, row_start, csr);

    // layer 1 + layer 2 over all rows (fp16 gather, f32 accumulate)
    spmm_kernel<0><<<37500, 256, 0, stream>>>(x0h, item_emb, x1h, acc, row_start, csr);
    spmm_kernel<1><<<37500, 256, 0, stream>>>(x1h, nullptr, x2h, acc, row_start, csr);
    // layer 3: item rows + queried users in one dispatch
    tail3_kernel<<<ITEM_BLKS + QB / 4, 256, 0, stream>>>(x2h, acc, row_start, csr,
                                                         items_h, user_emb, x1h,
                                                         users, ug_h);

    rating_kernel<<<dim3(RIT, QB / 64), 256, 0, stream>>>(items_h, ug_h, (float*)d_out);
}